// Round 1
// baseline (473.716 us; speedup 1.0000x reference)
//
#include <hip/hip_runtime.h>
#include <cstdint>
#include <cstddef>

#define NTOK 8192
#define DMODEL 1024

typedef _Float16 half8 __attribute__((ext_vector_type(8)));
typedef short short8 __attribute__((ext_vector_type(8)));
typedef unsigned short ushort8 __attribute__((ext_vector_type(8)));
typedef float f32x4 __attribute__((ext_vector_type(4)));

using gptr_as1 = const __attribute__((address_space(1))) void*;
using lptr_as3 = __attribute__((address_space(3))) void*;

template <typename T> struct V8T;
template <> struct V8T<_Float16> { using type = half8; };
template <> struct V8T<short>    { using type = short8; };

__device__ __forceinline__ f32x4 mfma16(half8 a, half8 b, f32x4 c) {
  return __builtin_amdgcn_mfma_f32_16x16x32_f16(a, b, c, 0, 0, 0);
}
__device__ __forceinline__ f32x4 mfma16(short8 a, short8 b, f32x4 c) {
  return __builtin_amdgcn_mfma_f32_16x16x32_bf16(a, b, c, 0, 0, 0);
}

__device__ __forceinline__ unsigned short f2bf(float f) {
  unsigned u = __float_as_uint(f);
  u += 0x7fffu + ((u >> 16) & 1u);
  return (unsigned short)(u >> 16);
}
__device__ __forceinline__ float bf2f(unsigned short b) {
  return __uint_as_float(((unsigned)b) << 16);
}

struct h4 { _Float16 x, y, z, w; };

__global__ void k_f32_to_f16(const float* __restrict__ in, h4* __restrict__ out, int n4) {
  int idx = blockIdx.x * blockDim.x + threadIdx.x;
  int stride = gridDim.x * blockDim.x;
  for (int i = idx; i < n4; i += stride) {
    float4 v = reinterpret_cast<const float4*>(in)[i];
    h4 o;
    o.x = (_Float16)v.x; o.y = (_Float16)v.y;
    o.z = (_Float16)v.z; o.w = (_Float16)v.w;
    out[i] = o;
  }
}

// C = A @ B^T.  A: [M x K] (lda), B: [N x K] (ldb), both row-major K-contiguous.
// m97 structure: 128x128 tile, BK=64, 4 waves (2x2), 4x4 16x16x32 fragments/wave,
// global_load_lds width=16 staging, 2 barriers per K-step.
// EPI 0: C fp16 (ldc)      EPI 1: C^T bf16 (stride ldc)
// EPI 2: P = exp(C-40) bf16 (ldc)   EPI 3: out fp32 = C / lvec[row] (ldc)
template <typename T, int EPI>
__global__ __launch_bounds__(256, 2) void gemm_bt(
    const T* __restrict__ A, const T* __restrict__ B, void* __restrict__ C,
    const float* __restrict__ lvec, int K, int lda, int ldb, int ldc)
{
  __shared__ __align__(16) T As[128 * 64];
  __shared__ __align__(16) T Bs[128 * 64];

  const int tid  = threadIdx.x;
  const int lane = tid & 63;
  const int wave = tid >> 6;
  const int wr = wave >> 1, wc = wave & 1;
  const int fq = lane >> 4, fr = lane & 15;
  const int brow = blockIdx.x * 128;
  const int bcol = blockIdx.y * 128;

  f32x4 acc[4][4] = {};

  const int nkb = K >> 6;
  for (int kb = 0; kb < nkb; ++kb) {
#pragma unroll
    for (int p = 0; p < 4; ++p) {
      const int t   = p * 256 + tid;
      const int row = t >> 3;          // 8 threads per 64-elem row
      const int col = (t & 7) * 8;
      const T* ga = A + (size_t)(brow + row) * lda + kb * 64 + col;
      const T* gb = B + (size_t)(bcol + row) * ldb + kb * 64 + col;
      __builtin_amdgcn_global_load_lds((gptr_as1)ga, (lptr_as3)(As + t * 8), 16, 0, 0);
      __builtin_amdgcn_global_load_lds((gptr_as1)gb, (lptr_as3)(Bs + t * 8), 16, 0, 0);
    }
    __syncthreads();  // compiler drains vmcnt before s_barrier
#pragma unroll
    for (int kk = 0; kk < 2; ++kk) {
      typename V8T<T>::type a[4], b[4];
#pragma unroll
      for (int i = 0; i < 4; ++i) {
        a[i] = *reinterpret_cast<const typename V8T<T>::type*>(
            &As[(wr * 64 + i * 16 + fr) * 64 + kk * 32 + fq * 8]);
        b[i] = *reinterpret_cast<const typename V8T<T>::type*>(
            &Bs[(wc * 64 + i * 16 + fr) * 64 + kk * 32 + fq * 8]);
      }
#pragma unroll
      for (int m = 0; m < 4; ++m)
#pragma unroll
        for (int n = 0; n < 4; ++n)
          acc[m][n] = mfma16(a[m], b[n], acc[m][n]);
    }
    __syncthreads();
  }

  // epilogue: C/D layout col=lane&15, row=(lane>>4)*4+j (m89-verified)
#pragma unroll
  for (int m = 0; m < 4; ++m) {
#pragma unroll
    for (int n = 0; n < 4; ++n) {
      const int r0 = brow + wr * 64 + m * 16 + fq * 4;
      const int c  = bcol + wc * 64 + n * 16 + fr;
      if constexpr (EPI == 0) {
        _Float16* Cc = (_Float16*)C;
#pragma unroll
        for (int j = 0; j < 4; ++j)
          Cc[(size_t)(r0 + j) * ldc + c] = (_Float16)acc[m][n][j];
      } else if constexpr (EPI == 1) {
        unsigned short* Cc = (unsigned short*)C;
        ushort4 pk;
        pk.x = f2bf(acc[m][n][0]); pk.y = f2bf(acc[m][n][1]);
        pk.z = f2bf(acc[m][n][2]); pk.w = f2bf(acc[m][n][3]);
        *reinterpret_cast<ushort4*>(&Cc[(size_t)c * ldc + r0]) = pk;
      } else if constexpr (EPI == 2) {
        unsigned short* Cc = (unsigned short*)C;
#pragma unroll
        for (int j = 0; j < 4; ++j) {
          // exp(S - 40) = exp2(S*log2e - 40*log2e)
          float e = exp2f(acc[m][n][j] * 1.4426950408889634f - 57.707801635558536f);
          Cc[(size_t)(r0 + j) * ldc + c] = f2bf(e);
        }
      } else {
        float* Cc = (float*)C;
#pragma unroll
        for (int j = 0; j < 4; ++j)
          Cc[(size_t)(r0 + j) * ldc + c] = acc[m][n][j] / lvec[r0 + j];
      }
    }
  }
}

// one wave per row, rows = grid.x*4
__global__ __launch_bounds__(256) void k_rowsum(
    const unsigned short* __restrict__ P, float* __restrict__ l, int cols)
{
  const int lane = threadIdx.x & 63;
  const int row  = blockIdx.x * 4 + (threadIdx.x >> 6);
  const unsigned short* p = P + (size_t)row * cols;
  float s = 0.f;
  for (int c = lane * 8; c < cols; c += 512) {
    ushort8 v = *reinterpret_cast<const ushort8*>(p + c);
#pragma unroll
    for (int j = 0; j < 8; ++j) s += bf2f(v[j]);
  }
#pragma unroll
  for (int off = 32; off > 0; off >>= 1) s += __shfl_xor(s, off, 64);
  if (lane == 0) l[row] = s;
}

extern "C" void kernel_launch(void* const* d_in, const int* in_sizes, int n_in,
                              void* d_out, int out_size, void* d_ws, size_t ws_size,
                              hipStream_t stream)
{
  const float* x  = (const float*)d_in[0];
  const float* Wq = (const float*)d_in[1];
  const float* Wk = (const float*)d_in[2];
  const float* Wv = (const float*)d_in[3];
  float* out = (float*)d_out;
  char* ws = (char*)d_ws;

  // workspace layout (bytes)
  _Float16* xh  = (_Float16*)(ws);                         // 16 MB
  _Float16* wqh = (_Float16*)(ws + 16777216);              // 2 MB
  _Float16* wkh = (_Float16*)(ws + 16777216 + 2097152);    // 2 MB
  _Float16* wvh = (_Float16*)(ws + 16777216 + 4194304);    // 2 MB
  _Float16* qh  = (_Float16*)(ws + 23068672);              // 16 MB
  _Float16* kh  = (_Float16*)(ws + 39845888);              // 16 MB
  unsigned short* vt = (unsigned short*)(ws + 56623104);   // 16 MB (bf16 V^T [1024][8192])
  float* l = (float*)(ws + 73400320);                      // 32 KB
  unsigned short* P = (unsigned short*)(ws + 73433088);    // CH x 8192 bf16

  // chunk rows for the materialized-P region, sized from available workspace
  size_t avail = ws_size > 73433088 ? ws_size - 73433088 : 0;
  long long chl = (long long)(avail / (NTOK * 2)) & ~127LL;
  int CH = (int)(chl > NTOK ? NTOK : chl);
  if (CH < 128) CH = 128;

  // 1) fp32 -> fp16 conversions
  k_f32_to_f16<<<2048, 256, 0, stream>>>(x,  (h4*)xh,  NTOK * DMODEL / 4);
  k_f32_to_f16<<<256, 256, 0, stream>>>(Wq, (h4*)wqh, DMODEL * DMODEL / 4);
  k_f32_to_f16<<<256, 256, 0, stream>>>(Wk, (h4*)wkh, DMODEL * DMODEL / 4);
  k_f32_to_f16<<<256, 256, 0, stream>>>(Wv, (h4*)wvh, DMODEL * DMODEL / 4);

  // 2) QKV projections: Q,K fp16; V stored bf16 transposed for the PV GEMM
  gemm_bt<_Float16, 0><<<dim3(64, 8), 256, 0, stream>>>(xh, wqh, qh, nullptr, DMODEL, DMODEL, DMODEL, DMODEL);
  gemm_bt<_Float16, 0><<<dim3(64, 8), 256, 0, stream>>>(xh, wkh, kh, nullptr, DMODEL, DMODEL, DMODEL, DMODEL);
  gemm_bt<_Float16, 1><<<dim3(64, 8), 256, 0, stream>>>(xh, wvh, vt, nullptr, DMODEL, DMODEL, DMODEL, NTOK);

  // 3) per row-chunk: P = exp(Q K^T - 40), l = rowsum(P), out = (P V) / l
  for (int row0 = 0; row0 < NTOK; row0 += CH) {
    int rows = (NTOK - row0 < CH) ? (NTOK - row0) : CH;
    gemm_bt<_Float16, 2><<<dim3(rows / 128, 64), 256, 0, stream>>>(
        qh + (size_t)row0 * DMODEL, kh, P, nullptr, DMODEL, DMODEL, DMODEL, NTOK);
    k_rowsum<<<rows / 4, 256, 0, stream>>>(P, l + row0, NTOK);
    gemm_bt<short, 3><<<dim3(rows / 128, 8), 256, 0, stream>>>(
        (const short*)P, (const short*)vt, out + (size_t)row0 * DMODEL, l + row0,
        NTOK, NTOK, NTOK, DMODEL);
  }
}

// Round 2
// 458.905 us; speedup vs baseline: 1.0323x; 1.0323x over previous
//
#include <hip/hip_runtime.h>
#include <cstdint>
#include <cstddef>

#define NTOK 8192
#define DMODEL 1024

typedef _Float16 half8 __attribute__((ext_vector_type(8)));
typedef short short8 __attribute__((ext_vector_type(8)));
typedef unsigned short ushort8 __attribute__((ext_vector_type(8)));
typedef float f32x4 __attribute__((ext_vector_type(4)));

using gptr_as1 = const __attribute__((address_space(1))) void*;
using lptr_as3 = __attribute__((address_space(3))) void*;

template <typename T> struct V8T;
template <> struct V8T<_Float16> { using type = half8; };
template <> struct V8T<short>    { using type = short8; };

__device__ __forceinline__ f32x4 mfma16(half8 a, half8 b, f32x4 c) {
  return __builtin_amdgcn_mfma_f32_16x16x32_f16(a, b, c, 0, 0, 0);
}
__device__ __forceinline__ f32x4 mfma16(short8 a, short8 b, f32x4 c) {
  return __builtin_amdgcn_mfma_f32_16x16x32_bf16(a, b, c, 0, 0, 0);
}

__device__ __forceinline__ unsigned short f2bf(float f) {
  unsigned u = __float_as_uint(f);
  u += 0x7fffu + ((u >> 16) & 1u);
  return (unsigned short)(u >> 16);
}

struct h4 { _Float16 x, y, z, w; };

__global__ void k_f32_to_f16(const float* __restrict__ in, h4* __restrict__ out, int n4) {
  int idx = blockIdx.x * blockDim.x + threadIdx.x;
  int stride = gridDim.x * blockDim.x;
  for (int i = idx; i < n4; i += stride) {
    float4 v = reinterpret_cast<const float4*>(in)[i];
    h4 o;
    o.x = (_Float16)v.x; o.y = (_Float16)v.y;
    o.z = (_Float16)v.z; o.w = (_Float16)v.w;
    out[i] = o;
  }
}

// C = A @ B^T.  A: [M x K] (lda), B: [N x K] (ldb), both row-major K-contiguous.
// m97 structure: 128x128 tile, BK=64, 4 waves (2x2), 4x4 16x16x32 frags/wave.
// EPI 2: P = exp(C-40) bf16 (ldc) + per-block partial row sums into C2 (Pl)
// EPI 3: out fp32 = C / lvec[row]                (single-shot PV, chunked path)
// EPI 4: split-K PV: fp32 C (z==0) / C2 (z==1), both / lvec[row]
// EPI 5: fused QKV: C=Q fp16, C2=K fp16, C3=V^T bf16 (transposed store)
template <typename T, int EPI, bool SWAPXY>
__global__ __launch_bounds__(256, 2) void gemm_bt(
    const T* __restrict__ A, const T* __restrict__ B,
    void* __restrict__ C, void* __restrict__ C2, void* __restrict__ C3,
    const float* __restrict__ lvec, int K, int lda, int ldb, int ldc, int koffz)
{
  __shared__ __align__(16) T As[128 * 64];
  __shared__ __align__(16) T Bs[128 * 64];

  const int tid  = threadIdx.x;
  const int lane = tid & 63;
  const int wave = tid >> 6;
  const int wr = wave >> 1, wc = wave & 1;
  const int fq = lane >> 4, fr = lane & 15;
  const int bxr = SWAPXY ? blockIdx.y : blockIdx.x;   // row-panel index
  const int bxc = SWAPXY ? blockIdx.x : blockIdx.y;   // col-panel index
  const int brow = bxr * 128;
  const int bcol = bxc * 128;
  const int koff = blockIdx.z * koffz;

  f32x4 acc[4][4] = {};

  const int nkb = K >> 6;
  for (int kb = 0; kb < nkb; ++kb) {
#pragma unroll
    for (int p = 0; p < 4; ++p) {
      const int t   = p * 256 + tid;
      const int row = t >> 3;          // 8 threads per 64-elem row
      const int col = (t & 7) * 8;
      const T* ga = A + (size_t)(brow + row) * lda + koff + kb * 64 + col;
      const T* gb = B + (size_t)(bcol + row) * ldb + koff + kb * 64 + col;
      __builtin_amdgcn_global_load_lds((gptr_as1)ga, (lptr_as3)(As + t * 8), 16, 0, 0);
      __builtin_amdgcn_global_load_lds((gptr_as1)gb, (lptr_as3)(Bs + t * 8), 16, 0, 0);
    }
    __syncthreads();
#pragma unroll
    for (int kk = 0; kk < 2; ++kk) {
      typename V8T<T>::type a[4], b[4];
#pragma unroll
      for (int i = 0; i < 4; ++i) {
        a[i] = *reinterpret_cast<const typename V8T<T>::type*>(
            &As[(wr * 64 + i * 16 + fr) * 64 + kk * 32 + fq * 8]);
        b[i] = *reinterpret_cast<const typename V8T<T>::type*>(
            &Bs[(wc * 64 + i * 16 + fr) * 64 + kk * 32 + fq * 8]);
      }
#pragma unroll
      for (int m = 0; m < 4; ++m)
#pragma unroll
        for (int n = 0; n < 4; ++n)
          acc[m][n] = mfma16(a[m], b[n], acc[m][n]);
    }
    __syncthreads();
  }

  // epilogue: C/D layout col=lane&15, row=(lane>>4)*4+j (m89-verified)
  if constexpr (EPI == 2) {
    unsigned short* Cc = (unsigned short*)C;
    float* Pl = (float*)C2;
    float ps[4][4];
#pragma unroll
    for (int m = 0; m < 4; ++m)
#pragma unroll
      for (int j = 0; j < 4; ++j) ps[m][j] = 0.f;
#pragma unroll
    for (int m = 0; m < 4; ++m) {
#pragma unroll
      for (int n = 0; n < 4; ++n) {
        const int r0 = brow + wr * 64 + m * 16 + fq * 4;
        const int c  = bcol + wc * 64 + n * 16 + fr;
#pragma unroll
        for (int j = 0; j < 4; ++j) {
          // exp(S - 40) = exp2(S*log2e - 40*log2e)
          float e = exp2f(acc[m][n][j] * 1.4426950408889634f - 57.707801635558536f);
          Cc[(size_t)(r0 + j) * ldc + c] = f2bf(e);
          ps[m][j] += e;
        }
      }
    }
    // reduce across the 16 lanes (fr) of each fq sub-group; all lanes get sum
#pragma unroll
    for (int m = 0; m < 4; ++m)
#pragma unroll
      for (int j = 0; j < 4; ++j) {
        float s = ps[m][j];
        s += __shfl_xor(s, 1, 64);
        s += __shfl_xor(s, 2, 64);
        s += __shfl_xor(s, 4, 64);
        s += __shfl_xor(s, 8, 64);
        ps[m][j] = s;
      }
    if (fr == 0) {
      const int pidx = bxc * 2 + wc;   // which 64-col slice of the 8192
#pragma unroll
      for (int m = 0; m < 4; ++m) {
        const int r0 = brow + wr * 64 + m * 16 + fq * 4;
#pragma unroll
        for (int j = 0; j < 4; ++j)
          Pl[(size_t)pidx * NTOK + r0 + j] = ps[m][j];
      }
    }
  } else if constexpr (EPI == 3) {
    float* Cc = (float*)C;
#pragma unroll
    for (int m = 0; m < 4; ++m)
#pragma unroll
      for (int n = 0; n < 4; ++n) {
        const int r0 = brow + wr * 64 + m * 16 + fq * 4;
        const int c  = bcol + wc * 64 + n * 16 + fr;
#pragma unroll
        for (int j = 0; j < 4; ++j)
          Cc[(size_t)(r0 + j) * ldc + c] = acc[m][n][j] / lvec[r0 + j];
      }
  } else if constexpr (EPI == 4) {
    float* Cc = (float*)(blockIdx.z ? C2 : C);
#pragma unroll
    for (int m = 0; m < 4; ++m)
#pragma unroll
      for (int n = 0; n < 4; ++n) {
        const int r0 = brow + wr * 64 + m * 16 + fq * 4;
        const int c  = bcol + wc * 64 + n * 16 + fr;
#pragma unroll
        for (int j = 0; j < 4; ++j)
          Cc[(size_t)(r0 + j) * ldc + c] = acc[m][n][j] / lvec[r0 + j];
      }
  } else {  // EPI 5: fused QKV epilogue, block-uniform branch by bcol range
    if (bcol < DMODEL) {
      _Float16* Cc = (_Float16*)C;
#pragma unroll
      for (int m = 0; m < 4; ++m)
#pragma unroll
        for (int n = 0; n < 4; ++n) {
          const int r0 = brow + wr * 64 + m * 16 + fq * 4;
          const int c  = bcol + wc * 64 + n * 16 + fr;
#pragma unroll
          for (int j = 0; j < 4; ++j)
            Cc[(size_t)(r0 + j) * DMODEL + c] = (_Float16)acc[m][n][j];
        }
    } else if (bcol < 2 * DMODEL) {
      _Float16* Cc = (_Float16*)C2;
#pragma unroll
      for (int m = 0; m < 4; ++m)
#pragma unroll
        for (int n = 0; n < 4; ++n) {
          const int r0 = brow + wr * 64 + m * 16 + fq * 4;
          const int c  = bcol + wc * 64 + n * 16 + fr - DMODEL;
#pragma unroll
          for (int j = 0; j < 4; ++j)
            Cc[(size_t)(r0 + j) * DMODEL + c] = (_Float16)acc[m][n][j];
        }
    } else {
      unsigned short* Cc = (unsigned short*)C3;
#pragma unroll
      for (int m = 0; m < 4; ++m)
#pragma unroll
        for (int n = 0; n < 4; ++n) {
          const int r0 = brow + wr * 64 + m * 16 + fq * 4;
          const int c  = bcol + wc * 64 + n * 16 + fr - 2 * DMODEL;
          ushort4 pk;
          pk.x = f2bf(acc[m][n][0]); pk.y = f2bf(acc[m][n][1]);
          pk.z = f2bf(acc[m][n][2]); pk.w = f2bf(acc[m][n][3]);
          *reinterpret_cast<ushort4*>(&Cc[(size_t)c * NTOK + r0]) = pk;
        }
    }
  }
}

// l[r] = sum over 128 column-slice partials
__global__ __launch_bounds__(256) void k_reduce_l(
    const float* __restrict__ Pl, float* __restrict__ l, int rows)
{
  int r = blockIdx.x * 256 + threadIdx.x;
  if (r < rows) {
    float s = 0.f;
#pragma unroll 8
    for (int p = 0; p < 128; ++p) s += Pl[(size_t)p * NTOK + r];
    l[r] = s;
  }
}

// out += p1 (fp32, vectorized)
__global__ __launch_bounds__(256) void k_add_out(
    float* __restrict__ out, const float* __restrict__ p1, int n4)
{
  int idx = blockIdx.x * blockDim.x + threadIdx.x;
  int stride = gridDim.x * blockDim.x;
  for (int i = idx; i < n4; i += stride) {
    float4 a = reinterpret_cast<float4*>(out)[i];
    float4 b = reinterpret_cast<const float4*>(p1)[i];
    a.x += b.x; a.y += b.y; a.z += b.z; a.w += b.w;
    reinterpret_cast<float4*>(out)[i] = a;
  }
}

extern "C" void kernel_launch(void* const* d_in, const int* in_sizes, int n_in,
                              void* d_out, int out_size, void* d_ws, size_t ws_size,
                              hipStream_t stream)
{
  const float* x  = (const float*)d_in[0];
  const float* Wq = (const float*)d_in[1];
  const float* Wk = (const float*)d_in[2];
  const float* Wv = (const float*)d_in[3];
  float* out = (float*)d_out;
  char* ws = (char*)d_ws;

  // workspace layout (bytes):
  //  [0,16M)   xh fp16           (dead after proj; overlaid by p1 in full path)
  //  [16M,22M) packed W fp16     (dead after proj; overlaid by Pl after QK)
  //  [22M,38M) Q fp16            (dead after QK in full path)
  //  [38M,54M) K fp16
  //  [54M,70M) V^T bf16 [1024][8192]
  //  [70M,+32K) l fp32
  //  [72M, +CH*16KB) P bf16
  //  p1 overlay at [0,32M) — split-K partial, full path only
  _Float16* xh  = (_Float16*)(ws);
  _Float16* wpk = (_Float16*)(ws + (16u << 20));
  _Float16* qh  = (_Float16*)(ws + (22u << 20));
  _Float16* kh  = (_Float16*)(ws + (38u << 20));
  unsigned short* vt = (unsigned short*)(ws + (54u << 20));
  float* l  = (float*)(ws + (70u << 20));
  float* Pl = (float*)(ws + (16u << 20));   // overlays wpk (dead by QK time)
  unsigned short* P = (unsigned short*)(ws + (72u << 20));
  float* p1 = (float*)ws;                   // overlays xh..qh (dead by PV time)

  size_t poff = (size_t)(72u << 20);
  size_t avail = ws_size > poff ? ws_size - poff : 0;
  long long chl = (long long)(avail / (NTOK * 2)) & ~127LL;
  int CH = (int)(chl > NTOK ? NTOK : chl);
  if (CH < 128) CH = 128;

  // 1) fp32 -> fp16 conversions (weights packed [Wq;Wk;Wv] = [3072][1024])
  k_f32_to_f16<<<2048, 256, 0, stream>>>(x,  (h4*)xh, NTOK * DMODEL / 4);
  k_f32_to_f16<<<256, 256, 0, stream>>>(Wq, (h4*)(wpk),                   DMODEL * DMODEL / 4);
  k_f32_to_f16<<<256, 256, 0, stream>>>(Wk, (h4*)(wpk + DMODEL * DMODEL), DMODEL * DMODEL / 4);
  k_f32_to_f16<<<256, 256, 0, stream>>>(Wv, (h4*)(wpk + 2 * DMODEL * DMODEL), DMODEL * DMODEL / 4);

  // 2) fused QKV projection: one pass over x, 1536 blocks
  gemm_bt<_Float16, 5, false><<<dim3(64, 24), 256, 0, stream>>>(
      xh, wpk, qh, kh, vt, nullptr, DMODEL, DMODEL, DMODEL, DMODEL, 0);

  if (CH >= NTOK) {
    // full path: single QK^T + fused rowsum, split-K=2 PV
    gemm_bt<_Float16, 2, false><<<dim3(64, 64), 256, 0, stream>>>(
        qh, kh, P, Pl, nullptr, nullptr, DMODEL, DMODEL, DMODEL, NTOK, 0);
    k_reduce_l<<<NTOK / 256, 256, 0, stream>>>(Pl, l, NTOK);
    gemm_bt<short, 4, true><<<dim3(8, 64, 2), 256, 0, stream>>>(
        (const short*)P, (const short*)vt, out, p1, nullptr, l,
        NTOK / 2, NTOK, NTOK, DMODEL, NTOK / 2);
    k_add_out<<<2048, 256, 0, stream>>>(out, p1, NTOK * DMODEL / 4);
  } else {
    // chunked fallback (small workspace): per-chunk QK -> l -> PV
    for (int row0 = 0; row0 < NTOK; row0 += CH) {
      int rows = (NTOK - row0 < CH) ? (NTOK - row0) : CH;
      gemm_bt<_Float16, 2, false><<<dim3(rows / 128, 64), 256, 0, stream>>>(
          qh + (size_t)row0 * DMODEL, kh, P, Pl, nullptr, nullptr,
          DMODEL, DMODEL, DMODEL, NTOK, 0);
      k_reduce_l<<<(rows + 255) / 256, 256, 0, stream>>>(Pl, l + row0, rows);
      gemm_bt<short, 3, true><<<dim3(8, rows / 128), 256, 0, stream>>>(
          (const short*)P, (const short*)vt, out + (size_t)row0 * DMODEL,
          nullptr, nullptr, l + row0, NTOK, NTOK, NTOK, DMODEL, 0);
    }
  }
}